// Round 11
// baseline (138.914 us; speedup 1.0000x reference)
//
#include <hip/hip_runtime.h>

#define B_ROWS 8192
#define FEAT   256
#define NBLK   1024        // snn blocks; 4160 rounds -> 4-5 per block
#define NJTILE 128         // 64-col j-tiles

typedef float f32x4 __attribute__((ext_vector_type(4)));
typedef _Float16 f16x8 __attribute__((ext_vector_type(8)));

typedef const __attribute__((address_space(1))) unsigned int* gas_ptr;
typedef __attribute__((address_space(3))) unsigned int* las_ptr;

__device__ __forceinline__ void gload_lds16(const void* g, void* l) {
  // HW semantics: LDS dest = wave-uniform base + lane*16 (global src per-lane)
  __builtin_amdgcn_global_load_lds((gas_ptr)g, (las_ptr)l, 16, 0, 0);
}

// cumulative round count before j-tile j (rounds (it,jt): it <= jt/2):
// C(2m) = m(m+1), C(2m+1) = (m+1)^2 ; C(128) = 4160
__device__ __forceinline__ int Cf(int j) {
  int m = j >> 1;
  return (j & 1) ? (m + 1) * (m + 1) : m * (m + 1);
}

// ---- kernel 1: fp16 convert -> FRAGMENT-NATIVE layout (R17, proven), row
// ssq, per-block partials; zeroes the atomic accumulators.
// xh chunk(C,kk) [1024 B]: byte l*16 = lane l's MFMA fragment for 16-row
// group C, k-slice kk  (C = row>>4; within: quad*256 + r15*16 + half*8).
__global__ __launch_bounds__(256) void prep_kernel(
    const float* __restrict__ x, unsigned short* __restrict__ xh,
    float* __restrict__ sq, float* __restrict__ part_s,
    float* __restrict__ part_q, float* __restrict__ col_den,
    float* __restrict__ col_num, float* __restrict__ row_den,
    float* __restrict__ row_num)
{
  int tid = threadIdx.x;
  int l = tid & 63, wid = tid >> 6;
  int row = blockIdx.x * 4 + wid;
  const float4* xv = (const float4*)(x + (size_t)row * FEAT);
  float4 v = xv[l];            // cols 4l .. 4l+3
  ushort4 u;
  u.x = __builtin_bit_cast(unsigned short, (_Float16)v.x);
  u.y = __builtin_bit_cast(unsigned short, (_Float16)v.y);
  u.z = __builtin_bit_cast(unsigned short, (_Float16)v.z);
  u.w = __builtin_bit_cast(unsigned short, (_Float16)v.w);
  // k0 = 4l: kk = l>>3, quad = (l>>1)&3, half-of-16B = l&1
  size_t off = ((size_t)(row >> 4) * 8 + (l >> 3)) * 1024
             + ((l >> 1) & 3) * 256 + (row & 15) * 16 + (l & 1) * 8;
  *(ushort4*)((char*)xh + off) = u;
  if (tid < 4) {
    int r4 = blockIdx.x * 4 + tid;
    col_den[r4] = 0.f; col_num[r4] = 0.f;
    row_den[r4] = 0.f; row_num[r4] = 0.f;
  }
  float ssq  = v.x*v.x + v.y*v.y + v.z*v.z + v.w*v.w;
  float ssum = v.x + v.y + v.z + v.w;
  #pragma unroll
  for (int m = 32; m; m >>= 1) {
    ssq  += __shfl_xor(ssq, m);
    ssum += __shfl_xor(ssum, m);
  }
  if (l == 0) sq[row] = ssq;
  __shared__ float red[8];
  if (l == 0) { red[wid*2] = ssum; red[wid*2+1] = ssq; }
  __syncthreads();
  if (tid == 0) {
    part_s[blockIdx.x] = red[0]+red[2]+red[4]+red[6];
    part_q[blockIdx.x] = red[1]+red[3]+red[5]+red[7];
  }
}

// ---- epilogue: wave tile 32(i) x 64(j). Row sums: per-round quad
// shuffle-reduce + atomicAdd (self-contained, proven R6b/R17).
// Col sums (!DIAG): accumulate per-lane into PERSISTENT cd/cn registers --
// flushed once per jt-group (R19: saves ~32 bpermutes + 16 atomics/round).
template<bool DIAG>
__device__ __forceinline__ void epilogue(
    const f32x4 (&acc)[2][4], const float* __restrict__ sq,
    const int* __restrict__ y, int j0, int l15, int l,
    int rbase, float nscale2,
    float* __restrict__ row_den, float* __restrict__ row_num,
    float (&cd)[4], float (&cn)[4])
{
  int jb = j0 + l15;
  float sqj[4]; int yj[4];
  #pragma unroll
  for (int cb = 0; cb < 4; ++cb) {
    int j = jb + cb*16;
    sqj[cb] = sq[j];
    yj[cb]  = y[j];
  }
  #pragma unroll
  for (int rb = 0; rb < 2; ++rb) {
    #pragma unroll
    for (int r = 0; r < 4; ++r) {
      int   ig = rbase + rb*16 + r;     // same for all 16 lanes of the quad
      float si = sq[ig];
      int   yi = y[ig];
      float dacc = 0.f, nacc = 0.f;
      #pragma unroll
      for (int cb = 0; cb < 4; ++cb) {
        float S  = acc[rb][cb][r];
        float d2 = fmaf(S, -2.0f, si + sqj[cb]);
        d2 = fmaxf(d2, 0.0f);
        float e  = __builtin_amdgcn_exp2f(__builtin_amdgcn_sqrtf(d2) * nscale2);
        bool same = (yi == yj[cb]);
        bool offd = !DIAG || (ig != jb + cb*16);
        dacc += offd ? e : 0.0f;
        nacc += (same && offd) ? e : 0.0f;
        if (!DIAG) {
          cd[cb] += e;
          cn[cb] += same ? e : 0.0f;
        }
      }
      #pragma unroll
      for (int m = 1; m <= 8; m <<= 1) {
        dacc += __shfl_xor(dacc, m);
        nacc += __shfl_xor(nacc, m);
      }
      if (l15 == 0) {
        atomicAdd(&row_den[ig], dacc);
        atomicAdd(&row_num[ig], nacc);
      }
    }
  }
}

__device__ __forceinline__ void flush_cols(
    float (&cd)[4], float (&cn)[4], int j0, int l,
    float* __restrict__ col_den, float* __restrict__ col_num)
{
  #pragma unroll
  for (int cb = 0; cb < 4; ++cb) {
    cd[cb] += __shfl_xor(cd[cb], 16);
    cd[cb] += __shfl_xor(cd[cb], 32);
    cn[cb] += __shfl_xor(cn[cb], 16);
    cn[cb] += __shfl_xor(cn[cb], 32);
  }
  if (l < 16) {
    #pragma unroll
    for (int cb = 0; cb < 4; ++cb) {
      atomicAdd(&col_den[j0 + cb*16 + l], cd[cb]);
      atomicAdd(&col_num[j0 + cb*16 + l], cn[cb]);
    }
  }
  #pragma unroll
  for (int cb = 0; cb < 4; ++cb) { cd[cb] = 0.f; cn[cb] = 0.f; }
}

// ---- kernel 2 (R19: 4-blocks/CU panel-resident): 4160 triangular rounds
// (it <= jt/2; 128-row x 64-col) flattened jt-major; block b owns
// [b*65>>4, (b+1)*65>>4) = 4-5 rounds (balanced). Consecutive rounds share
// jt -> the 32 KB fragment-native B panel staged once per jt-group; no
// barriers within a group. R18 lesson: at 2 blocks/CU the DS-pipe (~50K
// cyc) + VALU/trans (~40K) + MFMA (~15K) run SERIALLY (8 waves can't
// overlap them) -> per-tile wall stuck at 8.3K cyc. Lever: occupancy.
// amdgpu_waves_per_eu(4,4) = 4 blocks/CU with the correct VGPR cap of
// 512/4 = 128 (R18 fits: 124). launch_bounds' 2nd arg is NOT used -- its
// translation crushed VGPR to 64 and spilled (R1/R11).
// Grid 1024 = 4 blocks/CU exactly; LDS 4 x 32 KB = 128 KB <= 160.
__global__ __launch_bounds__(256)
__attribute__((amdgpu_waves_per_eu(4, 4)))
void snn_main(
    const unsigned short* __restrict__ xh, const float* __restrict__ sq,
    const int* __restrict__ y, const float* __restrict__ T,
    const float* __restrict__ part_s, const float* __restrict__ part_q,
    float* __restrict__ row_den, float* __restrict__ row_num,
    float* __restrict__ col_den, float* __restrict__ col_num)
{
  __shared__ __align__(16) char lB[32768];
  int tid = threadIdx.x;
  int l = tid & 63, wid = tid >> 6;     // wid = wave row strip (0..3)
  int quad = l >> 4, l15 = l & 15;
  int b = blockIdx.x;
  const char* xb = (const char*)xh;

  // scale from prep's 2048 partials (per-wave redundant; no barrier)
  float s_acc = 0.f, q_acc = 0.f;
  #pragma unroll
  for (int t = 0; t < 32; ++t) {
    s_acc += part_s[l + 64*t];
    q_acc += part_q[l + 64*t];
  }
  #pragma unroll
  for (int m = 1; m <= 32; m <<= 1) {
    s_acc += __shfl_xor(s_acc, m);
    q_acc += __shfl_xor(q_acc, m);
  }
  const double n = (double)B_ROWS * FEAT;
  double var = ((double)q_acc - (double)s_acc*(double)s_acc/n) / (n - 1.0);
  float stdv = (float)sqrt(var);
  float p10  = __builtin_amdgcn_exp2f(T[0] * 3.3219280948873623f);
  float nscale2 = -(p10 * 1.4426950408889634f / stdv);

  // segment [k0, kend) of the jt-major round list; decode k0 -> (jt, it)
  int k0   = (b * 65) >> 4;
  int kend = ((b + 1) * 65) >> 4;
  int jt = 2 * (int)__builtin_amdgcn_sqrtf((float)k0);
  if (jt > NJTILE - 1) jt = NJTILE - 1;
  while (jt + 1 < NJTILE && Cf(jt + 1) <= k0) ++jt;
  while (jt > 0 && Cf(jt) > k0) --jt;
  int it = k0 - Cf(jt);

  // stage B panel jt: 32 KB linear (fragment-native src == LDS layout)
  {
    const char* gB = xb + (size_t)jt * 32768;
    #pragma unroll
    for (int s = 0; s < 8; ++s) {
      int cc = wid*8 + s;
      gload_lds16(gB + cc*1024 + l*16, lB + cc*1024);
    }
  }
  __syncthreads();   // drains vmcnt: panel visible

  float cd[4], cn[4];
  #pragma unroll
  for (int cb = 0; cb < 4; ++cb) { cd[cb] = 0.f; cn[cb] = 0.f; }

  for (int k = k0; k < kend; ++k) {
    // A fragments for row-block it: chunk C = it*8 + wid*2 + rb, slice kk
    f16x8 areg[2][8];
    #pragma unroll
    for (int rb = 0; rb < 2; ++rb)
      #pragma unroll
      for (int kk = 0; kk < 8; ++kk)
        areg[rb][kk] = *(const f16x8*)(xb +
            ((size_t)(it*8 + wid*2 + rb) * 8 + kk) * 1024 + l*16);

    f32x4 acc[2][4];
    const f32x4 zero4 = {0.f, 0.f, 0.f, 0.f};
    #pragma unroll
    for (int rb = 0; rb < 2; ++rb)
      #pragma unroll
      for (int cb = 0; cb < 4; ++cb)
        acc[rb][cb] = zero4;

    #pragma unroll
    for (int kk = 0; kk < 8; ++kk) {
      f16x8 bv[4];
      #pragma unroll
      for (int cb = 0; cb < 4; ++cb)
        bv[cb] = *(const f16x8*)(lB + (cb*8 + kk)*1024 + l*16);
      #pragma unroll
      for (int rb = 0; rb < 2; ++rb)
        #pragma unroll
        for (int cb = 0; cb < 4; ++cb)
          acc[rb][cb] = __builtin_amdgcn_mfma_f32_16x16x32_f16(areg[rb][kk], bv[cb], acc[rb][cb], 0, 0, 0);
    }

    int j0 = jt * 64;
    int rbase = it*128 + wid*32 + quad*4;
    if ((jt >> 1) == it)
      epilogue<true >(acc, sq, y, j0, l15, l, rbase, nscale2,
                      row_den, row_num, cd, cn);
    else
      epilogue<false>(acc, sq, y, j0, l15, l, rbase, nscale2,
                      row_den, row_num, cd, cn);

    ++it;
    if (it > (jt >> 1)) {             // jt-group done
      flush_cols(cd, cn, j0, l, col_den, col_num);
      ++jt; it = 0;
      if (k + 1 < kend) {
        __syncthreads();              // all waves done reading old panel
        const char* gB = xb + (size_t)jt * 32768;
        #pragma unroll
        for (int s = 0; s < 8; ++s) {
          int cc = wid*8 + s;
          gload_lds16(gB + cc*1024 + l*16, lB + cc*1024);
        }
        __syncthreads();              // new panel visible
      }
    } else if (k + 1 == kend) {       // segment ends mid-group
      flush_cols(cd, cn, j0, l, col_den, col_num);
    }
  }
}

// ---- kernel 3: single 1024-thread block; reads only 4 x 32 KB.
// __builtin_amdgcn_logf is LOG2 -> scale by ln(2)  (R4/5/7/9 bug).
__global__ __launch_bounds__(1024) void final_kernel(
    const float* __restrict__ row_den, const float* __restrict__ row_num,
    const float* __restrict__ col_den, const float* __restrict__ col_num,
    float* __restrict__ out)
{
  int tid = threadIdx.x;
  float tot = 0.f;
  #pragma unroll
  for (int rr = 0; rr < 8; ++rr) {
    int row = tid + 1024*rr;
    float den = row_den[row] + col_den[row];
    float num = row_num[row] + col_num[row];
    if (num > 0.f)
      tot += 0.6931471805599453f *
             (__builtin_amdgcn_logf(num) - __builtin_amdgcn_logf(den));
  }
  #pragma unroll
  for (int m = 32; m; m >>= 1) tot += __shfl_xor(tot, m);
  __shared__ float red[16];
  if ((tid & 63) == 0) red[tid >> 6] = tot;
  __syncthreads();
  if (tid == 0) {
    float s = 0.f;
    #pragma unroll
    for (int w = 0; w < 16; ++w) s += red[w];
    out[0] = -s / 8192.0f;
  }
}

extern "C" void kernel_launch(void* const* d_in, const int* in_sizes, int n_in,
                              void* d_out, int out_size, void* d_ws, size_t ws_size,
                              hipStream_t stream)
{
  (void)in_sizes; (void)n_in; (void)out_size; (void)ws_size;
  const float* x  = (const float*)d_in[0];
  const int* y    = (const int*)d_in[1];   // int64 in reference -> int32 here (jax x64 off)
  const float* T  = (const float*)d_in[2];
  char* ws = (char*)d_ws;
  float* part_s = (float*)(ws + 1024);                   // 8 KB
  float* part_q = (float*)(ws + 1024 + 8192);            // 8 KB
  float* sq     = (float*)(ws + 32768);                  // 32 KB
  unsigned short* xh = (unsigned short*)(ws + 65536);    // 4 MB fp16 (fragment layout)
  float* col_den = (float*)(ws + 65536 + 4194304);       // 32 KB
  float* col_num = col_den + B_ROWS;                     // 32 KB
  float* row_den = col_num + B_ROWS;                     // 32 KB
  float* row_num = row_den + B_ROWS;                     // 32 KB

  hipLaunchKernelGGL(prep_kernel, dim3(B_ROWS/4), dim3(256), 0, stream,
                     x, xh, sq, part_s, part_q, col_den, col_num,
                     row_den, row_num);
  hipLaunchKernelGGL(snn_main, dim3(NBLK), dim3(256), 0, stream,
                     xh, sq, y, T, part_s, part_q, row_den, row_num,
                     col_den, col_num);
  hipLaunchKernelGGL(final_kernel, dim3(1), dim3(1024), 0, stream,
                     row_den, row_num, col_den, col_num, (float*)d_out);
}

// Round 12
// 107.510 us; speedup vs baseline: 1.2921x; 1.2921x over previous
//
#include <hip/hip_runtime.h>

#define B_ROWS 8192
#define FEAT   256
#define NBLK   512         // snn blocks; 4160 tiles -> 8.125 per block
#define NJTILE 128         // 64-col j-tiles

typedef float f32x4 __attribute__((ext_vector_type(4)));
typedef _Float16 f16x8 __attribute__((ext_vector_type(8)));

typedef const __attribute__((address_space(1))) unsigned int* gas_ptr;
typedef __attribute__((address_space(3))) unsigned int* las_ptr;

__device__ __forceinline__ void gload_lds16(const void* g, void* l) {
  // HW semantics: LDS dest = wave-uniform base + lane*16 (global src per-lane)
  __builtin_amdgcn_global_load_lds((gas_ptr)g, (las_ptr)l, 16, 0, 0);
}

// cumulative tiles before row it (row r owns jt in [2r,128), 128-2r tiles)
__device__ __forceinline__ int Rc(int it) { return it * (129 - it); }

// ---- kernel 1: fp16 convert -> FRAGMENT-NATIVE layout (proven R17/R19),
// row ssq, per-block partials; zeroes the atomic accumulators.
// xh chunk(C,kk) [1024 B]: byte l*16 = lane l's MFMA fragment for 16-row
// group C, k-slice kk  (C = row>>4; within: quad*256 + r15*16 + half*8).
__global__ __launch_bounds__(256) void prep_kernel(
    const float* __restrict__ x, unsigned short* __restrict__ xh,
    float* __restrict__ sq, float* __restrict__ part_s,
    float* __restrict__ part_q, float* __restrict__ col_den,
    float* __restrict__ col_num, float* __restrict__ row_den,
    float* __restrict__ row_num)
{
  int tid = threadIdx.x;
  int l = tid & 63, wid = tid >> 6;
  int row = blockIdx.x * 4 + wid;
  const float4* xv = (const float4*)(x + (size_t)row * FEAT);
  float4 v = xv[l];            // cols 4l .. 4l+3
  ushort4 u;
  u.x = __builtin_bit_cast(unsigned short, (_Float16)v.x);
  u.y = __builtin_bit_cast(unsigned short, (_Float16)v.y);
  u.z = __builtin_bit_cast(unsigned short, (_Float16)v.z);
  u.w = __builtin_bit_cast(unsigned short, (_Float16)v.w);
  // k0 = 4l: kk = l>>3, quad = (l>>1)&3, half-of-16B = l&1
  size_t off = ((size_t)(row >> 4) * 8 + (l >> 3)) * 1024
             + ((l >> 1) & 3) * 256 + (row & 15) * 16 + (l & 1) * 8;
  *(ushort4*)((char*)xh + off) = u;
  if (tid < 4) {
    int r4 = blockIdx.x * 4 + tid;
    col_den[r4] = 0.f; col_num[r4] = 0.f;
    row_den[r4] = 0.f; row_num[r4] = 0.f;
  }
  float ssq  = v.x*v.x + v.y*v.y + v.z*v.z + v.w*v.w;
  float ssum = v.x + v.y + v.z + v.w;
  #pragma unroll
  for (int m = 32; m; m >>= 1) {
    ssq  += __shfl_xor(ssq, m);
    ssum += __shfl_xor(ssum, m);
  }
  if (l == 0) sq[row] = ssq;
  __shared__ float red[8];
  if (l == 0) { red[wid*2] = ssum; red[wid*2+1] = ssq; }
  __syncthreads();
  if (tid == 0) {
    part_s[blockIdx.x] = red[0]+red[2]+red[4]+red[6];
    part_q[blockIdx.x] = red[1]+red[3]+red[5]+red[7];
  }
}

// ---- epilogue: wave tile 32(i) x 64(j). Row sums -> PERSISTENT registers
// (sden/snum, flushed once per run -- R10's cheap path). Far tiles also
// credit cols (e(i,j)=e(j,i)): per-tile quad reduce + atomicAdd (proven
// R15 path). DIAG: band tile (jt>>1 == it), mask i==j, rows only.
template<bool DIAG>
__device__ __forceinline__ void epilogue(
    const f32x4 (&acc)[2][4], const float* __restrict__ sq,
    const int* __restrict__ y, int j0, int l15, int l,
    int rbase, const float (&sqi)[8], const int (&yiv)[8],
    float (&sden)[8], float (&snum)[8], float nscale2,
    float* __restrict__ col_den, float* __restrict__ col_num)
{
  int jb = j0 + l15;
  float sqj[4]; int yj[4];
  #pragma unroll
  for (int cb = 0; cb < 4; ++cb) {
    int j = jb + cb*16;
    sqj[cb] = sq[j];
    yj[cb]  = y[j];
  }
  float cd[4], cn[4];
  if (!DIAG) {
    #pragma unroll
    for (int cb = 0; cb < 4; ++cb) { cd[cb] = 0.f; cn[cb] = 0.f; }
  }
  #pragma unroll
  for (int rb = 0; rb < 2; ++rb) {
    #pragma unroll
    for (int r = 0; r < 4; ++r) {
      float si = sqi[rb*4+r];
      int   ig = rbase + rb*16 + r;
      int   yi = yiv[rb*4+r];
      float dacc = 0.f, nacc = 0.f;
      #pragma unroll
      for (int cb = 0; cb < 4; ++cb) {
        float S  = acc[rb][cb][r];
        float d2 = fmaf(S, -2.0f, si + sqj[cb]);
        d2 = fmaxf(d2, 0.0f);
        float e  = __builtin_amdgcn_exp2f(__builtin_amdgcn_sqrtf(d2) * nscale2);
        bool same = (yi == yj[cb]);
        bool offd = !DIAG || (ig != jb + cb*16);
        dacc += offd ? e : 0.0f;
        nacc += (same && offd) ? e : 0.0f;
        if (!DIAG) {
          cd[cb] += e;
          cn[cb] += same ? e : 0.0f;
        }
      }
      sden[rb*4+r] += dacc;
      snum[rb*4+r] += nacc;
    }
  }
  if (!DIAG) {
    #pragma unroll
    for (int cb = 0; cb < 4; ++cb) {
      cd[cb] += __shfl_xor(cd[cb], 16);
      cd[cb] += __shfl_xor(cd[cb], 32);
      cn[cb] += __shfl_xor(cn[cb], 16);
      cn[cb] += __shfl_xor(cn[cb], 32);
    }
    if (l < 16) {
      #pragma unroll
      for (int cb = 0; cb < 4; ++cb) {
        atomicAdd(&col_den[j0 + cb*16 + l], cd[cb]);
        atomicAdd(&col_num[j0 + cb*16 + l], cn[cb]);
      }
    }
  }
}

// ---- one pipelined run: row-block `it`, contiguous j-tiles [jt0, jt0+nt).
// R10's proven 2-barrier structure: stage(jt) || epilogue(jt-1) || MFMA(jt).
// areg loaded once; row sums persist in registers, flushed at run end.
__device__ __forceinline__ void process_run(
    int it, int jt0, int nt, const char* __restrict__ xb,
    const float* __restrict__ sq, const int* __restrict__ y,
    float nscale2, int l, int wid, int quad, int l15,
    float* __restrict__ row_den, float* __restrict__ row_num,
    float* __restrict__ col_den, float* __restrict__ col_num,
    char* lB)
{
  // A fragments: chunk C = it*8 + wid*2 + rb, slice kk, byte l*16
  f16x8 areg[2][8];
  #pragma unroll
  for (int rb = 0; rb < 2; ++rb)
    #pragma unroll
    for (int kk = 0; kk < 8; ++kk)
      areg[rb][kk] = *(const f16x8*)(xb +
          ((size_t)(it*8 + wid*2 + rb) * 8 + kk) * 1024 + l*16);

  // per-lane row stats (persistent for the run)
  float sqi[8]; int yiv[8];
  int rbase = it*128 + wid*32 + quad*4;
  #pragma unroll
  for (int rb = 0; rb < 2; ++rb)
    #pragma unroll
    for (int r = 0; r < 4; ++r) {
      int idx = rbase + rb*16 + r;
      sqi[rb*4+r] = sq[idx];
      yiv[rb*4+r] = y[idx];
    }

  float sden[8], snum[8];
  #pragma unroll
  for (int v = 0; v < 8; ++v) { sden[v] = 0.f; snum[v] = 0.f; }
  f32x4 acc[2][4];
  const f32x4 zero4 = {0.f, 0.f, 0.f, 0.f};

  for (int n = 0; n < nt; ++n) {
    int jt = jt0 + n;

    __syncthreads();   // all waves done reading lB (previous tile / run)
    // stage B panel jt: 32 KB linear (fragment-native src == LDS layout)
    {
      const char* gB = xb + (size_t)jt * 32768;
      #pragma unroll
      for (int s = 0; s < 8; ++s) {
        int cc = wid*8 + s;
        gload_lds16(gB + cc*1024 + l*16, lB + cc*1024);
      }
    }

    if (n > 0) {
      int pjt = jt - 1;
      if ((pjt >> 1) == it)
        epilogue<true >(acc, sq, y, pjt*64, l15, l, rbase, sqi, yiv,
                        sden, snum, nscale2, col_den, col_num);
      else
        epilogue<false>(acc, sq, y, pjt*64, l15, l, rbase, sqi, yiv,
                        sden, snum, nscale2, col_den, col_num);
    }
    #pragma unroll
    for (int rb = 0; rb < 2; ++rb)
      #pragma unroll
      for (int cb = 0; cb < 4; ++cb)
        acc[rb][cb] = zero4;

    __syncthreads();   // drains vmcnt: B panel visible

    #pragma unroll
    for (int kk = 0; kk < 8; ++kk) {
      f16x8 bv[4];
      #pragma unroll
      for (int cb = 0; cb < 4; ++cb)
        bv[cb] = *(const f16x8*)(lB + (cb*8 + kk)*1024 + l*16);
      #pragma unroll
      for (int rb = 0; rb < 2; ++rb)
        #pragma unroll
        for (int cb = 0; cb < 4; ++cb)
          acc[rb][cb] = __builtin_amdgcn_mfma_f32_16x16x32_f16(areg[rb][kk], bv[cb], acc[rb][cb], 0, 0, 0);
    }
  }
  {
    int pjt = jt0 + nt - 1;
    if ((pjt >> 1) == it)
      epilogue<true >(acc, sq, y, pjt*64, l15, l, rbase, sqi, yiv,
                      sden, snum, nscale2, col_den, col_num);
    else
      epilogue<false>(acc, sq, y, pjt*64, l15, l, rbase, sqi, yiv,
                      sden, snum, nscale2, col_den, col_num);
  }

  // flush row sums: quad reduce + atomicAdd (rows shared across blocks)
  #pragma unroll
  for (int v = 0; v < 8; ++v) {
    #pragma unroll
    for (int m = 1; m <= 8; m <<= 1) {
      sden[v] += __shfl_xor(sden[v], m);
      snum[v] += __shfl_xor(snum[v], m);
    }
  }
  if (l15 == 0) {
    #pragma unroll
    for (int rb = 0; rb < 2; ++rb)
      #pragma unroll
      for (int r = 0; r < 4; ++r) {
        int ig = rbase + rb*16 + r;
        atomicAdd(&row_den[ig], sden[rb*4+r]);
        atomicAdd(&row_num[ig], snum[rb*4+r]);
      }
  }
}

// ---- kernel 2 (R20: it-major triangular segments, R10 pipeline): the 4160
// triangular tiles (it <= jt>>1; 128-row x 64-col) flattened IT-MAJOR; block
// b owns [b*65>>3, (b+1)*65>>3) = 8-9 contiguous tiles. 7/8 of blocks get a
// SINGLE 8-9 tile run -> one areg load, full-depth R10 pipeline (stage ||
// epilogue(prev) || MFMA). R11-R19 lessons: occupancy levers spill (VGPR
// demand ~124 vs 4-wave cap 128-eff-64, tried 3x); epilogue-after-MFMA
// schedules (R18/R19) serialize the sqrt->exp chains -> 8.3K cyc/tile vs
// R10's pipelined 4.5K. This keeps R10's rate on the half-size triangle.
__global__ __launch_bounds__(256, 2) void snn_main(
    const unsigned short* __restrict__ xh, const float* __restrict__ sq,
    const int* __restrict__ y, const float* __restrict__ T,
    const float* __restrict__ part_s, const float* __restrict__ part_q,
    float* __restrict__ row_den, float* __restrict__ row_num,
    float* __restrict__ col_den, float* __restrict__ col_num)
{
  __shared__ __align__(16) char lB[32768];
  int tid = threadIdx.x;
  int l = tid & 63, wid = tid >> 6;     // wid = wave row strip (0..3)
  int quad = l >> 4, l15 = l & 15;
  int b = blockIdx.x;
  const char* xb = (const char*)xh;

  // scale from prep's 2048 partials (per-wave redundant; no barrier)
  float s_acc = 0.f, q_acc = 0.f;
  #pragma unroll
  for (int t = 0; t < 32; ++t) {
    s_acc += part_s[l + 64*t];
    q_acc += part_q[l + 64*t];
  }
  #pragma unroll
  for (int m = 1; m <= 32; m <<= 1) {
    s_acc += __shfl_xor(s_acc, m);
    q_acc += __shfl_xor(q_acc, m);
  }
  const double n = (double)B_ROWS * FEAT;
  double var = ((double)q_acc - (double)s_acc*(double)s_acc/n) / (n - 1.0);
  float stdv = (float)sqrt(var);
  float p10  = __builtin_amdgcn_exp2f(T[0] * 3.3219280948873623f);
  float nscale2 = -(p10 * 1.4426950408889634f / stdv);

  // segment [k, kend) of the it-major tile list; decode k -> (it, jt)
  int k    = (b * 65) >> 3;
  int kend = ((b + 1) * 65) >> 3;
  int it = (int)((129.0f - __builtin_amdgcn_sqrtf(16641.0f - 4.0f*(float)k)) * 0.5f);
  if (it < 0) it = 0;
  if (it > 63) it = 63;
  while (it < 63 && Rc(it + 1) <= k) ++it;
  while (it > 0 && Rc(it) > k) --it;

  while (k < kend) {
    int jt0  = 2*it + (k - Rc(it));
    int rowe = Rc(it + 1);                 // first k of next row
    int stop = (kend < rowe) ? kend : rowe;
    int nt   = stop - k;                   // contiguous tiles in this run
    process_run(it, jt0, nt, xb, sq, y, nscale2, l, wid, quad, l15,
                row_den, row_num, col_den, col_num, lB);
    k = stop;
    ++it;
  }
}

// ---- kernel 3: single 1024-thread block; reads only 4 x 32 KB.
// __builtin_amdgcn_logf is LOG2 -> scale by ln(2)  (R4/5/7/9 bug).
__global__ __launch_bounds__(1024) void final_kernel(
    const float* __restrict__ row_den, const float* __restrict__ row_num,
    const float* __restrict__ col_den, const float* __restrict__ col_num,
    float* __restrict__ out)
{
  int tid = threadIdx.x;
  float tot = 0.f;
  #pragma unroll
  for (int rr = 0; rr < 8; ++rr) {
    int row = tid + 1024*rr;
    float den = row_den[row] + col_den[row];
    float num = row_num[row] + col_num[row];
    if (num > 0.f)
      tot += 0.6931471805599453f *
             (__builtin_amdgcn_logf(num) - __builtin_amdgcn_logf(den));
  }
  #pragma unroll
  for (int m = 32; m; m >>= 1) tot += __shfl_xor(tot, m);
  __shared__ float red[16];
  if ((tid & 63) == 0) red[tid >> 6] = tot;
  __syncthreads();
  if (tid == 0) {
    float s = 0.f;
    #pragma unroll
    for (int w = 0; w < 16; ++w) s += red[w];
    out[0] = -s / 8192.0f;
  }
}

extern "C" void kernel_launch(void* const* d_in, const int* in_sizes, int n_in,
                              void* d_out, int out_size, void* d_ws, size_t ws_size,
                              hipStream_t stream)
{
  (void)in_sizes; (void)n_in; (void)out_size; (void)ws_size;
  const float* x  = (const float*)d_in[0];
  const int* y    = (const int*)d_in[1];   // int64 in reference -> int32 here (jax x64 off)
  const float* T  = (const float*)d_in[2];
  char* ws = (char*)d_ws;
  float* part_s = (float*)(ws + 1024);                   // 8 KB
  float* part_q = (float*)(ws + 1024 + 8192);            // 8 KB
  float* sq     = (float*)(ws + 32768);                  // 32 KB
  unsigned short* xh = (unsigned short*)(ws + 65536);    // 4 MB fp16 (fragment layout)
  float* col_den = (float*)(ws + 65536 + 4194304);       // 32 KB
  float* col_num = col_den + B_ROWS;                     // 32 KB
  float* row_den = col_num + B_ROWS;                     // 32 KB
  float* row_num = row_den + B_ROWS;                     // 32 KB

  hipLaunchKernelGGL(prep_kernel, dim3(B_ROWS/4), dim3(256), 0, stream,
                     x, xh, sq, part_s, part_q, col_den, col_num,
                     row_den, row_num);
  hipLaunchKernelGGL(snn_main, dim3(NBLK), dim3(256), 0, stream,
                     xh, sq, y, T, part_s, part_q, row_den, row_num,
                     col_den, col_num);
  hipLaunchKernelGGL(final_kernel, dim3(1), dim3(1024), 0, stream,
                     row_den, row_num, col_den, col_num, (float*)d_out);
}